// Round 1
// baseline (15863.089 us; speedup 1.0000x reference)
//
#include <hip/hip_runtime.h>
#include <cstddef>
#include <cstdint>

constexpr int B_ = 8, P_ = 4096, K_ = 20, H_ = 64, C_ = 40;
constexpr int NPT = B_ * P_;
#define NEG_SLOPE 0.2f

// ---------------------------------------------------------------- d2 = sum(x*x)
__global__ __launch_bounds__(256) void d2_kernel(const float* __restrict__ x,
                                                 float* __restrict__ d2, int D) {
    int i = blockIdx.x * 256 + threadIdx.x;
    if (i >= NPT) return;
    const float* r = x + (size_t)i * D;
    float s = 0.f;
    for (int d = 0; d < D; ++d) { float v = r[d]; s += v * v; }
    d2[i] = s;
}

// ---------------------------------------------------------------- knn (2 queries / block)
// dist_ij = d2_i + d2_j - 2*dot  (same expansion as reference), self += 1e10
template <int D>
__global__ __launch_bounds__(256) void knn_kernel(const float* __restrict__ x,
                                                  const float* __restrict__ d2,
                                                  int* __restrict__ idx) {
    __shared__ float dist[2][P_];   // 32 KB
    __shared__ float q[2][D];
    __shared__ float qd2[2];

    int tid = threadIdx.x;
    int bq = blockIdx.x % (P_ / 2);
    int b  = blockIdx.x / (P_ / 2);
    int i0 = bq * 2;
    const float* xb  = x  + (size_t)b * P_ * D;
    const float* d2b = d2 + (size_t)b * P_;

    for (int t = tid; t < 2 * D; t += 256)
        q[t / D][t % D] = xb[(size_t)(i0 + t / D) * D + (t % D)];
    if (tid < 2) qd2[tid] = d2b[i0 + tid];
    __syncthreads();

    for (int j = tid; j < P_; j += 256) {
        float dot0 = 0.f, dot1 = 0.f;
        if constexpr (D == 3) {
            float a0 = xb[j * 3], a1 = xb[j * 3 + 1], a2 = xb[j * 3 + 2];
            dot0 = q[0][0] * a0 + q[0][1] * a1 + q[0][2] * a2;
            dot1 = q[1][0] * a0 + q[1][1] * a1 + q[1][2] * a2;
        } else {
            const float4* xr = (const float4*)(xb + (size_t)j * D);
#pragma unroll
            for (int d4 = 0; d4 < D / 4; ++d4) {
                float4 xv = xr[d4];
                float4 q0 = *(const float4*)&q[0][d4 * 4];
                float4 q1 = *(const float4*)&q[1][d4 * 4];
                dot0 += q0.x * xv.x + q0.y * xv.y + q0.z * xv.z + q0.w * xv.w;
                dot1 += q1.x * xv.x + q1.y * xv.y + q1.z * xv.z + q1.w * xv.w;
            }
        }
        float dj = d2b[j];
        float dd0 = (qd2[0] + dj) - 2.f * dot0;
        float dd1 = (qd2[1] + dj) - 2.f * dot1;
        if (j == i0)     dd0 += 1e10f;
        if (j == i0 + 1) dd1 += 1e10f;
        dist[0][j] = dd0;
        dist[1][j] = dd1;
    }
    __syncthreads();

    int w = tid >> 6, lane = tid & 63;
    if (w < 2) {
        float* dw = dist[w];
        int iq = i0 + w;
        for (int k = 0; k < K_; ++k) {
            float best = 3.0e38f; int bi = 0;
            for (int j = lane; j < P_; j += 64) {
                float v = dw[j];
                if (v < best) { best = v; bi = j; }
            }
#pragma unroll
            for (int s = 1; s < 64; s <<= 1) {
                float ob = __shfl_xor(best, s);
                int   oi = __shfl_xor(bi, s);
                if (ob < best || (ob == best && oi < bi)) { best = ob; bi = oi; }
            }
            if (lane == 0) {
                idx[(size_t)(b * P_ + iq) * K_ + k] = b * P_ + bi;  // global point id
                dw[bi] = 3.0e38f;  // remove; same-wave LDS is in-order
            }
        }
    }
}

// ---------------------------------------------------------------- edge conv
// out[p][h] = max_k leaky( sum_d xi[d]*W[d][h] + (xj[d]-xi[d])*W[DIN+d][h] + b[h] )
template <int DIN>
__global__ __launch_bounds__(256) void edgeconv_kernel(const float* __restrict__ xin,
                                                       const int* __restrict__ idx,
                                                       const float* __restrict__ W,
                                                       const float* __restrict__ bias,
                                                       float* __restrict__ xout) {
    __shared__ float sW[2 * DIN * H_];
    __shared__ float sxi[4][DIN];
    __shared__ float sdf[4][K_][DIN];

    int tid = threadIdx.x, lane = tid & 63, wv = tid >> 6;
    for (int t = tid; t < 2 * DIN * H_; t += 256) sW[t] = W[t];

    int gp = blockIdx.x * 4 + wv;
    float xi_r = 0.f;
    if (lane < DIN) {
        xi_r = xin[(size_t)gp * DIN + lane];
        sxi[wv][lane] = xi_r;
    }
    for (int k = 0; k < K_; ++k) {
        int j = idx[(size_t)gp * K_ + k];
        if (lane < DIN)
            sdf[wv][k][lane] = xin[(size_t)j * DIN + lane] - xi_r;
    }
    __syncthreads();

    int h = lane;
    float bs = bias[h];
    float amax = -3.4e38f;
    for (int k = 0; k < K_; ++k) {
        float acc = bs;
#pragma unroll
        for (int d = 0; d < DIN; ++d) {
            acc = fmaf(sxi[wv][d],    sW[d * H_ + h],          acc);
            acc = fmaf(sdf[wv][k][d], sW[(DIN + d) * H_ + h],  acc);
        }
        float v = acc > 0.f ? acc : NEG_SLOPE * acc;
        amax = fmaxf(amax, v);
    }
    xout[(size_t)gp * H_ + h] = amax;
}

// ---------------------------------------------------------------- GEMM: C = act(A @ W + b)
// A: [M,Kd] (or concat(x1,x2,x3) each width 64 when cat=1, Kd=192), W: [Kd,N]
// BM=64, BN=64, BK=16, 256 threads, 4x4 micro-tile
__global__ __launch_bounds__(256) void gemm_kernel(const float* __restrict__ A1,
                                                   const float* __restrict__ A2,
                                                   const float* __restrict__ A3,
                                                   int cat,
                                                   const float* __restrict__ Wm,
                                                   const float* __restrict__ bias,
                                                   float* __restrict__ Cm,
                                                   int M, int N, int Kd, int leaky) {
    __shared__ float sA[16][64];
    __shared__ float sB[16][64];

    int tid = threadIdx.x;
    int row0 = blockIdx.x * 64, col0 = blockIdx.y * 64;
    int tx = tid & 15, ty = tid >> 4;

    int lr  = tid >> 2;          // 0..63  (A row)
    int lk4 = (tid & 3) * 4;     // 0,4,8,12 (A k)
    int lkb = tid >> 4;          // 0..15  (B k)
    int lnb = (tid & 15) * 4;    // 0..60  (B col)

    float acc[4][4] = {};

    for (int k0 = 0; k0 < Kd; k0 += 16) {
        // stage A
        int arow = row0 + lr;
        int kk = k0 + lk4;
        const float* src;
        if (cat) {
            if (kk < 64)       src = A1 + (size_t)arow * 64 + kk;
            else if (kk < 128) src = A2 + (size_t)arow * 64 + (kk - 64);
            else               src = A3 + (size_t)arow * 64 + (kk - 128);
        } else {
            src = A1 + (size_t)arow * Kd + kk;
        }
        float4 av = *(const float4*)src;
        sA[lk4 + 0][lr] = av.x; sA[lk4 + 1][lr] = av.y;
        sA[lk4 + 2][lr] = av.z; sA[lk4 + 3][lr] = av.w;
        // stage B
        int bcol = col0 + lnb;
        float4 bv = make_float4(0.f, 0.f, 0.f, 0.f);
        if (bcol < N) bv = *(const float4*)(Wm + (size_t)(k0 + lkb) * N + bcol);
        *(float4*)&sB[lkb][lnb] = bv;
        __syncthreads();

#pragma unroll
        for (int kk2 = 0; kk2 < 16; ++kk2) {
            float4 a = *(const float4*)&sA[kk2][ty * 4];
            float4 bb = *(const float4*)&sB[kk2][tx * 4];
            acc[0][0] = fmaf(a.x, bb.x, acc[0][0]); acc[0][1] = fmaf(a.x, bb.y, acc[0][1]);
            acc[0][2] = fmaf(a.x, bb.z, acc[0][2]); acc[0][3] = fmaf(a.x, bb.w, acc[0][3]);
            acc[1][0] = fmaf(a.y, bb.x, acc[1][0]); acc[1][1] = fmaf(a.y, bb.y, acc[1][1]);
            acc[1][2] = fmaf(a.y, bb.z, acc[1][2]); acc[1][3] = fmaf(a.y, bb.w, acc[1][3]);
            acc[2][0] = fmaf(a.z, bb.x, acc[2][0]); acc[2][1] = fmaf(a.z, bb.y, acc[2][1]);
            acc[2][2] = fmaf(a.z, bb.z, acc[2][2]); acc[2][3] = fmaf(a.z, bb.w, acc[2][3]);
            acc[3][0] = fmaf(a.w, bb.x, acc[3][0]); acc[3][1] = fmaf(a.w, bb.y, acc[3][1]);
            acc[3][2] = fmaf(a.w, bb.z, acc[3][2]); acc[3][3] = fmaf(a.w, bb.w, acc[3][3]);
        }
        __syncthreads();
    }

    for (int i = 0; i < 4; ++i) {
        int row = row0 + ty * 4 + i;
        for (int j = 0; j < 4; ++j) {
            int col = col0 + tx * 4 + j;
            if (col < N) {
                float v = acc[i][j] + bias[col];
                if (leaky) v = v > 0.f ? v : NEG_SLOPE * v;
                Cm[(size_t)row * N + col] = v;
            }
        }
    }
}

// ---------------------------------------------------------------- log_softmax rows of 40
__global__ __launch_bounds__(256) void lsm_kernel(float* __restrict__ out) {
    int row = blockIdx.x * 4 + (threadIdx.x >> 6);
    int lane = threadIdx.x & 63;
    float v = -3.4e38f;
    if (lane < C_) v = out[(size_t)row * C_ + lane];
    float m = v;
#pragma unroll
    for (int s = 1; s < 64; s <<= 1) m = fmaxf(m, __shfl_xor(m, s));
    float e = (lane < C_) ? expf(v - m) : 0.f;
    float sum = e;
#pragma unroll
    for (int s = 1; s < 64; s <<= 1) sum += __shfl_xor(sum, s);
    if (lane < C_) out[(size_t)row * C_ + lane] = v - m - logf(sum);
}

// ----------------------------------------------------------------
extern "C" void kernel_launch(void* const* d_in, const int* in_sizes, int n_in,
                              void* d_out, int out_size, void* d_ws, size_t ws_size,
                              hipStream_t stream) {
    const float* x   = (const float*)d_in[0];
    const float* W1  = (const float*)d_in[2];
    const float* b1  = (const float*)d_in[3];
    const float* W2  = (const float*)d_in[4];
    const float* b2  = (const float*)d_in[5];
    const float* W3  = (const float*)d_in[6];
    const float* b3  = (const float*)d_in[7];
    const float* Wl  = (const float*)d_in[8];
    const float* bl  = (const float*)d_in[9];
    const float* Wm1 = (const float*)d_in[10];
    const float* bm1 = (const float*)d_in[11];
    const float* Wm2 = (const float*)d_in[12];
    const float* bm2 = (const float*)d_in[13];
    const float* Wo  = (const float*)d_in[14];
    const float* bo  = (const float*)d_in[15];
    float* out = (float*)d_out;

    char* ws = (char*)d_ws;
    float* x1   = (float*)(ws);                       // 32768*64*4 = 8 MB
    float* x2   = (float*)(ws + 8388608);
    float* x3   = (float*)(ws + 16777216);
    int*   idx  = (int*)  (ws + 25165824);            // 32768*20*4
    float* d2   = (float*)(ws + 27787264);            // 32768*4
    float* bufA = (float*)(ws + 27918336);            // 4096*1024*4
    float* bufB = (float*)(ws + 44695552);            // 4096*256*4
    float* bufC = (float*)(ws + 48889856);            // 4096*128*4

    // ---- edge conv 1 (d=3)
    d2_kernel<<<NPT / 256, 256, 0, stream>>>(x, d2, 3);
    knn_kernel<3><<<NPT / 2, 256, 0, stream>>>(x, d2, idx);
    edgeconv_kernel<3><<<NPT / 4, 256, 0, stream>>>(x, idx, W1, b1, x1);
    // ---- edge conv 2 (d=64)
    d2_kernel<<<NPT / 256, 256, 0, stream>>>(x1, d2, 64);
    knn_kernel<64><<<NPT / 2, 256, 0, stream>>>(x1, d2, idx);
    edgeconv_kernel<64><<<NPT / 4, 256, 0, stream>>>(x1, idx, W2, b2, x2);
    // ---- edge conv 3 (d=64)
    d2_kernel<<<NPT / 256, 256, 0, stream>>>(x2, d2, 64);
    knn_kernel<64><<<NPT / 2, 256, 0, stream>>>(x2, d2, idx);
    edgeconv_kernel<64><<<NPT / 4, 256, 0, stream>>>(x2, idx, W3, b3, x3);

    // ---- MLP head in 8 row-chunks of 4096
    for (int c = 0; c < 8; ++c) {
        size_t r0 = (size_t)c * 4096;
        gemm_kernel<<<dim3(64, 16), 256, 0, stream>>>(x1 + r0 * 64, x2 + r0 * 64, x3 + r0 * 64,
                                                      1, Wl, bl, bufA, 4096, 1024, 192, 1);
        gemm_kernel<<<dim3(64, 4), 256, 0, stream>>>(bufA, nullptr, nullptr,
                                                     0, Wm1, bm1, bufB, 4096, 256, 1024, 1);
        gemm_kernel<<<dim3(64, 2), 256, 0, stream>>>(bufB, nullptr, nullptr,
                                                     0, Wm2, bm2, bufC, 4096, 128, 256, 1);
        gemm_kernel<<<dim3(64, 1), 256, 0, stream>>>(bufC, nullptr, nullptr,
                                                     0, Wo, bo, out + r0 * C_, 4096, 40, 128, 0);
    }
    lsm_kernel<<<NPT / 4, 256, 0, stream>>>(out);
}

// Round 3
// 5171.793 us; speedup vs baseline: 3.0672x; 3.0672x over previous
//
#include <hip/hip_runtime.h>
#include <cstddef>
#include <cstdint>

constexpr int B_ = 8, P_ = 4096, K_ = 20, H_ = 64, C_ = 40;
constexpr int NPT = B_ * P_;
constexpr int NSEG = 4, SEGLEN = P_ / NSEG;   // 1024 candidates per segment
#define NEG_SLOPE 0.2f

typedef unsigned long long u64;
typedef unsigned int u32;

// ---------------------------------------------------------------- d2 = sum(x*x)
__global__ __launch_bounds__(256) void d2_kernel(const float* __restrict__ x,
                                                 float* __restrict__ d2, int D) {
    int i = blockIdx.x * 256 + threadIdx.x;
    if (i >= NPT) return;
    const float* r = x + (size_t)i * D;
    float s = 0.f;
    for (int d = 0; d < D; ++d) { float v = r[d]; s += v * v; }
    d2[i] = s;
}

// ---------------------------------------------------------------- knn segment pass
// One wave (64 threads) = 64 queries; candidates wave-uniform (scalar loads).
// Each thread keeps exact top-20 of its segment as sortable u64 keys
// (dist_bits<<32 | j) -> min-20 by (dist, idx): identical tie-break to top_k.
// Slots are replace-max-by-equality; ALL keys (including init sentinels) must
// be pairwise distinct -> sentinels (inf<<32)|(0xFFFFFFFF-s).
template <int D>
__global__ __launch_bounds__(64) void knn_seg_kernel(const float* __restrict__ x,
                                                     const float* __restrict__ d2,
                                                     u64* __restrict__ seglist) {
    int qg  = blockIdx.x / NSEG;      // query group (64 queries)
    int seg = blockIdx.x % NSEG;
    int b   = qg >> 6;                // 64 groups per batch -> scalar batch id
    int lane = threadIdx.x;
    int ql  = ((qg & 63) << 6) + lane;          // query id within batch
    int q   = (b << 12) + ql;                   // global query id

    const float* xb  = x  + (size_t)b * P_ * D;   // scalar base
    const float* d2b = d2 + (size_t)b * P_;       // scalar base

    float qf[D];
#pragma unroll
    for (int d = 0; d < D; ++d) qf[d] = xb[(size_t)ql * D + d];
    float qd2 = d2b[ql];

    u64 lst[K_];
#pragma unroll
    for (int s = 0; s < K_; ++s)
        lst[s] = (0x7F800000ULL << 32) | (u64)(0xFFFFFFFFu - s);   // distinct sentinels
    u64 kmax = (0x7F800000ULL << 32) | 0xFFFFFFFFULL;              // the largest one

    int j0 = seg * SEGLEN;
    for (int j = j0; j < j0 + SEGLEN; ++j) {
        const float* cp = xb + (size_t)j * D;    // wave-uniform address
        float a0 = 0.f, a1 = 0.f, a2 = 0.f, a3 = 0.f;
        if constexpr (D == 3) {
            a0 = qf[0] * cp[0];
            a1 = qf[1] * cp[1];
            a2 = qf[2] * cp[2];
        } else {
#pragma unroll
            for (int d4 = 0; d4 < D; d4 += 4) {
                float4 cv = *(const float4*)(cp + d4);
                a0 = fmaf(qf[d4 + 0], cv.x, a0);
                a1 = fmaf(qf[d4 + 1], cv.y, a1);
                a2 = fmaf(qf[d4 + 2], cv.z, a2);
                a3 = fmaf(qf[d4 + 3], cv.w, a3);
            }
        }
        float dot = (a0 + a1) + (a2 + a3);
        float dist = (qd2 + d2b[j]) - 2.f * dot;
        if (j == ql) dist += 1e10f;              // self mask (same as reference)
        dist = fmaxf(dist, 0.0f);                // keep f32->u32 key monotonic
        u64 key = ((u64)__float_as_uint(dist) << 32) | (u32)j;
        bool ins = key < kmax;
        if (__any(ins)) {
            u64 km = kmax;
#pragma unroll
            for (int s = 0; s < K_; ++s) {       // unique keys -> exactly one slot == km
                bool repl = ins && (lst[s] == km);
                lst[s] = repl ? key : lst[s];
            }
            u64 m = lst[0];
#pragma unroll
            for (int s = 1; s < K_; ++s) m = lst[s] > m ? lst[s] : m;
            kmax = m;
        }
    }

    u64* outp = seglist + ((size_t)q * NSEG + seg) * K_;
#pragma unroll
    for (int s = 0; s < K_; ++s) outp[s] = lst[s];
}

// ---------------------------------------------------------------- merge NSEG segment lists
__global__ __launch_bounds__(64) void knn_merge_kernel(const u64* __restrict__ seglist,
                                                       int* __restrict__ idx) {
    __shared__ u64 keys[64][NSEG * K_ + 1];      // +1 pad: 2-way conflicts only
    int lane = threadIdx.x;
    int q = blockIdx.x * 64 + lane;
    const u64* src = seglist + (size_t)q * NSEG * K_;
    for (int s = 0; s < NSEG * K_; ++s) keys[lane][s] = src[s];
    int base = (q >> 12) << 12;                  // b * 4096
    int* op = idx + (size_t)q * K_;
    for (int k = 0; k < K_; ++k) {
        u64 m = keys[lane][0]; int sm = 0;
        for (int s = 1; s < NSEG * K_; ++s) {
            u64 v = keys[lane][s];
            if (v < m) { m = v; sm = s; }
        }
        keys[lane][sm] = ~0ULL;
        op[k] = base + (int)(m & 0xFFFFFFFFu);   // global point id
    }
}

// ---------------------------------------------------------------- edge conv
template <int DIN>
__global__ __launch_bounds__(256) void edgeconv_kernel(const float* __restrict__ xin,
                                                       const int* __restrict__ idx,
                                                       const float* __restrict__ W,
                                                       const float* __restrict__ bias,
                                                       float* __restrict__ xout) {
    __shared__ float sW[2 * DIN * H_];
    __shared__ float sxi[4][DIN];
    __shared__ float sdf[4][K_][DIN];

    int tid = threadIdx.x, lane = tid & 63, wv = tid >> 6;
    for (int t = tid; t < 2 * DIN * H_; t += 256) sW[t] = W[t];

    int gp = blockIdx.x * 4 + wv;
    float xi_r = 0.f;
    if (lane < DIN) {
        xi_r = xin[(size_t)gp * DIN + lane];
        sxi[wv][lane] = xi_r;
    }
    for (int k = 0; k < K_; ++k) {
        int j = idx[(size_t)gp * K_ + k];
        if (lane < DIN)
            sdf[wv][k][lane] = xin[(size_t)j * DIN + lane] - xi_r;
    }
    __syncthreads();

    int h = lane;
    float bs = bias[h];
    float amax = -3.4e38f;
    for (int k = 0; k < K_; ++k) {
        float acc = bs;
#pragma unroll
        for (int d = 0; d < DIN; ++d) {
            acc = fmaf(sxi[wv][d],    sW[d * H_ + h],          acc);
            acc = fmaf(sdf[wv][k][d], sW[(DIN + d) * H_ + h],  acc);
        }
        float v = acc > 0.f ? acc : NEG_SLOPE * acc;
        amax = fmaxf(amax, v);
    }
    xout[(size_t)gp * H_ + h] = amax;
}

// ---------------------------------------------------------------- GEMM: C = act(A @ W + b)
__global__ __launch_bounds__(256) void gemm_kernel(const float* __restrict__ A1,
                                                   const float* __restrict__ A2,
                                                   const float* __restrict__ A3,
                                                   int cat,
                                                   const float* __restrict__ Wm,
                                                   const float* __restrict__ bias,
                                                   float* __restrict__ Cm,
                                                   int M, int N, int Kd, int leaky) {
    __shared__ float sA[16][64];
    __shared__ float sB[16][64];

    int tid = threadIdx.x;
    int row0 = blockIdx.x * 64, col0 = blockIdx.y * 64;
    int tx = tid & 15, ty = tid >> 4;

    int lr  = tid >> 2;
    int lk4 = (tid & 3) * 4;
    int lkb = tid >> 4;
    int lnb = (tid & 15) * 4;

    float acc[4][4] = {};

    for (int k0 = 0; k0 < Kd; k0 += 16) {
        int arow = row0 + lr;
        int kk = k0 + lk4;
        const float* src;
        if (cat) {
            if (kk < 64)       src = A1 + (size_t)arow * 64 + kk;
            else if (kk < 128) src = A2 + (size_t)arow * 64 + (kk - 64);
            else               src = A3 + (size_t)arow * 64 + (kk - 128);
        } else {
            src = A1 + (size_t)arow * Kd + kk;
        }
        float4 av = *(const float4*)src;
        sA[lk4 + 0][lr] = av.x; sA[lk4 + 1][lr] = av.y;
        sA[lk4 + 2][lr] = av.z; sA[lk4 + 3][lr] = av.w;
        int bcol = col0 + lnb;
        float4 bv = make_float4(0.f, 0.f, 0.f, 0.f);
        if (bcol < N) bv = *(const float4*)(Wm + (size_t)(k0 + lkb) * N + bcol);
        *(float4*)&sB[lkb][lnb] = bv;
        __syncthreads();

#pragma unroll
        for (int kk2 = 0; kk2 < 16; ++kk2) {
            float4 a = *(const float4*)&sA[kk2][ty * 4];
            float4 bb = *(const float4*)&sB[kk2][tx * 4];
            acc[0][0] = fmaf(a.x, bb.x, acc[0][0]); acc[0][1] = fmaf(a.x, bb.y, acc[0][1]);
            acc[0][2] = fmaf(a.x, bb.z, acc[0][2]); acc[0][3] = fmaf(a.x, bb.w, acc[0][3]);
            acc[1][0] = fmaf(a.y, bb.x, acc[1][0]); acc[1][1] = fmaf(a.y, bb.y, acc[1][1]);
            acc[1][2] = fmaf(a.y, bb.z, acc[1][2]); acc[1][3] = fmaf(a.y, bb.w, acc[1][3]);
            acc[2][0] = fmaf(a.z, bb.x, acc[2][0]); acc[2][1] = fmaf(a.z, bb.y, acc[2][1]);
            acc[2][2] = fmaf(a.z, bb.z, acc[2][2]); acc[2][3] = fmaf(a.z, bb.w, acc[2][3]);
            acc[3][0] = fmaf(a.w, bb.x, acc[3][0]); acc[3][1] = fmaf(a.w, bb.y, acc[3][1]);
            acc[3][2] = fmaf(a.w, bb.z, acc[3][2]); acc[3][3] = fmaf(a.w, bb.w, acc[3][3]);
        }
        __syncthreads();
    }

    for (int i = 0; i < 4; ++i) {
        int row = row0 + ty * 4 + i;
        for (int j = 0; j < 4; ++j) {
            int col = col0 + tx * 4 + j;
            if (col < N) {
                float v = acc[i][j] + bias[col];
                if (leaky) v = v > 0.f ? v : NEG_SLOPE * v;
                Cm[(size_t)row * N + col] = v;
            }
        }
    }
}

// ---------------------------------------------------------------- log_softmax rows of 40
__global__ __launch_bounds__(256) void lsm_kernel(float* __restrict__ out) {
    int row = blockIdx.x * 4 + (threadIdx.x >> 6);
    int lane = threadIdx.x & 63;
    float v = -3.4e38f;
    if (lane < C_) v = out[(size_t)row * C_ + lane];
    float m = v;
#pragma unroll
    for (int s = 1; s < 64; s <<= 1) m = fmaxf(m, __shfl_xor(m, s));
    float e = (lane < C_) ? expf(v - m) : 0.f;
    float sum = e;
#pragma unroll
    for (int s = 1; s < 64; s <<= 1) sum += __shfl_xor(sum, s);
    if (lane < C_) out[(size_t)row * C_ + lane] = v - m - logf(sum);
}

// ----------------------------------------------------------------
extern "C" void kernel_launch(void* const* d_in, const int* in_sizes, int n_in,
                              void* d_out, int out_size, void* d_ws, size_t ws_size,
                              hipStream_t stream) {
    const float* x   = (const float*)d_in[0];
    const float* W1  = (const float*)d_in[2];
    const float* b1  = (const float*)d_in[3];
    const float* W2  = (const float*)d_in[4];
    const float* b2  = (const float*)d_in[5];
    const float* W3  = (const float*)d_in[6];
    const float* b3  = (const float*)d_in[7];
    const float* Wl  = (const float*)d_in[8];
    const float* bl  = (const float*)d_in[9];
    const float* Wm1 = (const float*)d_in[10];
    const float* bm1 = (const float*)d_in[11];
    const float* Wm2 = (const float*)d_in[12];
    const float* bm2 = (const float*)d_in[13];
    const float* Wo  = (const float*)d_in[14];
    const float* bo  = (const float*)d_in[15];
    float* out = (float*)d_out;

    char* ws = (char*)d_ws;
    float* x1   = (float*)(ws);                       // 8 MB
    float* x2   = (float*)(ws + 8388608);
    float* x3   = (float*)(ws + 16777216);
    int*   idx  = (int*)  (ws + 25165824);            // 2.6 MB
    float* d2   = (float*)(ws + 27787264);            // 128 KB
    float* bufA = (float*)(ws + 27918336);            // 16 MB (MLP phase)
    float* bufB = (float*)(ws + 44695552);            // 4 MB
    float* bufC = (float*)(ws + 48889856);            // 2 MB
    u64*   segl = (u64*)  (ws + 27918336);            // 21 MB, aliases bufA/B (knn phase only)

    const int SEG_GRID = (NPT / 64) * NSEG;           // 2048
    const int MRG_GRID = NPT / 64;                    // 512

    // ---- edge conv 1 (d=3)
    d2_kernel<<<NPT / 256, 256, 0, stream>>>(x, d2, 3);
    knn_seg_kernel<3><<<SEG_GRID, 64, 0, stream>>>(x, d2, segl);
    knn_merge_kernel<<<MRG_GRID, 64, 0, stream>>>(segl, idx);
    edgeconv_kernel<3><<<NPT / 4, 256, 0, stream>>>(x, idx, W1, b1, x1);
    // ---- edge conv 2 (d=64)
    d2_kernel<<<NPT / 256, 256, 0, stream>>>(x1, d2, 64);
    knn_seg_kernel<64><<<SEG_GRID, 64, 0, stream>>>(x1, d2, segl);
    knn_merge_kernel<<<MRG_GRID, 64, 0, stream>>>(segl, idx);
    edgeconv_kernel<64><<<NPT / 4, 256, 0, stream>>>(x1, idx, W2, b2, x2);
    // ---- edge conv 3 (d=64)
    d2_kernel<<<NPT / 256, 256, 0, stream>>>(x2, d2, 64);
    knn_seg_kernel<64><<<SEG_GRID, 64, 0, stream>>>(x2, d2, segl);
    knn_merge_kernel<<<MRG_GRID, 64, 0, stream>>>(segl, idx);
    edgeconv_kernel<64><<<NPT / 4, 256, 0, stream>>>(x2, idx, W3, b3, x3);

    // ---- MLP head in 8 row-chunks of 4096
    for (int c = 0; c < 8; ++c) {
        size_t r0 = (size_t)c * 4096;
        gemm_kernel<<<dim3(64, 16), 256, 0, stream>>>(x1 + r0 * 64, x2 + r0 * 64, x3 + r0 * 64,
                                                      1, Wl, bl, bufA, 4096, 1024, 192, 1);
        gemm_kernel<<<dim3(64, 4), 256, 0, stream>>>(bufA, nullptr, nullptr,
                                                     0, Wm1, bm1, bufB, 4096, 256, 1024, 1);
        gemm_kernel<<<dim3(64, 2), 256, 0, stream>>>(bufB, nullptr, nullptr,
                                                     0, Wm2, bm2, bufC, 4096, 128, 256, 1);
        gemm_kernel<<<dim3(64, 1), 256, 0, stream>>>(bufC, nullptr, nullptr,
                                                     0, Wo, bo, out + r0 * C_, 4096, 40, 128, 0);
    }
    lsm_kernel<<<NPT / 4, 256, 0, stream>>>(out);
}

// Round 4
// 4390.184 us; speedup vs baseline: 3.6133x; 1.1780x over previous
//
#include <hip/hip_runtime.h>
#include <cstddef>
#include <cstdint>

constexpr int B_ = 8, P_ = 4096, K_ = 20, H_ = 64, C_ = 40;
constexpr int NPT = B_ * P_;
constexpr int NSEG = 4, SEGLEN = P_ / NSEG;   // 1024 candidates per segment
#define NEG_SLOPE 0.2f

typedef unsigned long long u64;
typedef unsigned int u32;
typedef float v2f __attribute__((ext_vector_type(2)));

__device__ inline const float* uniform_ptr(const float* p) {
    // force pointer into SGPRs so candidate loads become scalar (s_load)
    uint64_t v = (uint64_t)p;
    u32 lo = __builtin_amdgcn_readfirstlane((u32)v);
    u32 hi = __builtin_amdgcn_readfirstlane((u32)(v >> 32));
    return (const float*)(((uint64_t)hi << 32) | lo);
}

// ---------------------------------------------------------------- d2 = sum(x*x)
__global__ __launch_bounds__(256) void d2_kernel(const float* __restrict__ x,
                                                 float* __restrict__ d2, int D) {
    int i = blockIdx.x * 256 + threadIdx.x;
    if (i >= NPT) return;
    const float* r = x + (size_t)i * D;
    float s = 0.f;
    for (int d = 0; d < D; ++d) { float v = r[d]; s += v * v; }
    d2[i] = s;
}

// ---------------------------------------------------------------- knn segment pass
// One wave = 64 queries (features in VGPRs); candidates wave-uniform (scalar loads).
// Exact top-20 via replace-max list of sortable u64 keys (dist_bits<<32 | j);
// 2-deep per-lane pending buffer defers the expensive list update.
template <int D>
__global__ __launch_bounds__(64, 2) void knn_seg_kernel(const float* __restrict__ x,
                                                        const float* __restrict__ d2,
                                                        u64* __restrict__ seglist) {
    int qg  = blockIdx.x / NSEG;      // query group (64 queries)
    int seg = blockIdx.x % NSEG;
    int b   = qg >> 6;                // 64 groups per batch
    int lane = threadIdx.x;
    int ql  = ((qg & 63) << 6) + lane;          // query id within batch
    int q   = (b << 12) + ql;                   // global query id

    const float* xb  = x  + (size_t)b * P_ * D;
    const float* d2b = d2 + (size_t)b * P_;
    const float* xs  = uniform_ptr(xb);          // candidate base (SGPR)
    const float* d2s = uniform_ptr(d2b);

    float qf[D];
#pragma unroll
    for (int d = 0; d < D; ++d) qf[d] = xb[(size_t)ql * D + d];
    float qd2 = d2b[ql];

    u64 lst[K_];
#pragma unroll
    for (int s = 0; s < K_; ++s)
        lst[s] = (0x7F800000ULL << 32) | (u64)(0xFFFFFFFFu - s);   // distinct sentinels
    u64 kmax = (0x7F800000ULL << 32) | 0xFFFFFFFFULL;

    u64 p0 = ~0ULL, p1 = ~0ULL;   // pending (invalid sentinels always >= kmax)
    int pcnt = 0;

    int j0 = seg * SEGLEN;
    for (int j = j0; j < j0 + SEGLEN; ++j) {
        float dist;
        if constexpr (D == 3) {
            float a0 = qf[0] * xs[j * 3];
            float a1 = qf[1] * xs[j * 3 + 1];
            float a2 = qf[2] * xs[j * 3 + 2];
            dist = (qd2 + d2s[j]) - 2.f * (a0 + a1 + a2);
        } else {
            v2f acc0 = {0.f, 0.f}, acc1 = {0.f, 0.f};
            const v2f* cp = (const v2f*)(xs + (size_t)j * D);
#pragma unroll
            for (int d4 = 0; d4 < D / 4; ++d4) {
                v2f c0 = cp[d4 * 2], c1 = cp[d4 * 2 + 1];
                v2f q0 = {qf[d4 * 4 + 0], qf[d4 * 4 + 1]};
                v2f q1 = {qf[d4 * 4 + 2], qf[d4 * 4 + 3]};
                acc0 = acc0 + q0 * c0;    // -> v_pk_fma_f32 (ffp-contract)
                acc1 = acc1 + q1 * c1;
            }
            v2f acc = acc0 + acc1;
            dist = (qd2 + d2s[j]) - 2.f * (acc.x + acc.y);
        }
        if (j == ql) dist += 1e10f;              // self mask (same as reference)
        dist = fmaxf(dist, 0.0f);                // keep f32->u32 key monotonic
        u64 key = ((u64)__float_as_uint(dist) << 32) | (u32)j;

        bool pass = key < kmax;                  // conservative gate (kmax stale-high)
        p1 = pass ? p0 : p1;
        p0 = pass ? key : p0;
        pcnt = pass ? pcnt + 1 : pcnt;

        if (__any(pcnt >= 2)) {
            u64 e0 = p1, e1 = p0;                // older first (order irrelevant)
#pragma unroll
            for (int t = 0; t < 2; ++t) {
                u64 key2 = (t == 0) ? e0 : e1;
                bool ins = key2 < kmax;          // exact re-check vs current kmax
                if (__any(ins)) {
                    u64 km = kmax;
#pragma unroll
                    for (int s = 0; s < K_; ++s)
                        lst[s] = (ins && lst[s] == km) ? key2 : lst[s];
                    u64 m = lst[0];
#pragma unroll
                    for (int s = 1; s < K_; ++s) m = lst[s] > m ? lst[s] : m;
                    kmax = m;
                }
            }
            p0 = ~0ULL; p1 = ~0ULL; pcnt = 0;
        }
    }
    // final flush of leftovers
    {
        u64 e0 = p1, e1 = p0;
#pragma unroll
        for (int t = 0; t < 2; ++t) {
            u64 key2 = (t == 0) ? e0 : e1;
            bool ins = key2 < kmax;
            if (__any(ins)) {
                u64 km = kmax;
#pragma unroll
                for (int s = 0; s < K_; ++s)
                    lst[s] = (ins && lst[s] == km) ? key2 : lst[s];
                u64 m = lst[0];
#pragma unroll
                for (int s = 1; s < K_; ++s) m = lst[s] > m ? lst[s] : m;
                kmax = m;
            }
        }
    }

    u64* outp = seglist + ((size_t)q * NSEG + seg) * K_;
#pragma unroll
    for (int s = 0; s < K_; ++s) outp[s] = lst[s];
}

// ---------------------------------------------------------------- merge NSEG segment lists
__global__ __launch_bounds__(64, 2) void knn_merge_kernel(const u64* __restrict__ seglist,
                                                          int* __restrict__ idx) {
    __shared__ u64 keys[64][NSEG * K_ + 1];      // +1 pad: 2-way conflicts only
    int lane = threadIdx.x;
    int q = blockIdx.x * 64 + lane;
    const u64* src = seglist + (size_t)q * NSEG * K_;
    for (int s = 0; s < NSEG * K_; ++s) keys[lane][s] = src[s];
    int base = (q >> 12) << 12;                  // b * 4096
    int* op = idx + (size_t)q * K_;
    for (int k = 0; k < K_; ++k) {
        u64 m = keys[lane][0]; int sm = 0;
        for (int s = 1; s < NSEG * K_; ++s) {
            u64 v = keys[lane][s];
            if (v < m) { m = v; sm = s; }
        }
        keys[lane][sm] = ~0ULL;
        op[k] = base + (int)(m & 0xFFFFFFFFu);   // global point id
    }
}

// ---------------------------------------------------------------- edge conv
template <int DIN>
__global__ __launch_bounds__(256) void edgeconv_kernel(const float* __restrict__ xin,
                                                       const int* __restrict__ idx,
                                                       const float* __restrict__ W,
                                                       const float* __restrict__ bias,
                                                       float* __restrict__ xout) {
    __shared__ float sW[2 * DIN * H_];
    __shared__ float sxi[4][DIN];
    __shared__ float sdf[4][K_][DIN];

    int tid = threadIdx.x, lane = tid & 63, wv = tid >> 6;
    for (int t = tid; t < 2 * DIN * H_; t += 256) sW[t] = W[t];

    int gp = blockIdx.x * 4 + wv;
    float xi_r = 0.f;
    if (lane < DIN) {
        xi_r = xin[(size_t)gp * DIN + lane];
        sxi[wv][lane] = xi_r;
    }
    for (int k = 0; k < K_; ++k) {
        int j = idx[(size_t)gp * K_ + k];
        if (lane < DIN)
            sdf[wv][k][lane] = xin[(size_t)j * DIN + lane] - xi_r;
    }
    __syncthreads();

    int h = lane;
    float bs = bias[h];
    float amax = -3.4e38f;
    for (int k = 0; k < K_; ++k) {
        float acc = bs;
#pragma unroll
        for (int d = 0; d < DIN; ++d) {
            acc = fmaf(sxi[wv][d],    sW[d * H_ + h],          acc);
            acc = fmaf(sdf[wv][k][d], sW[(DIN + d) * H_ + h],  acc);
        }
        float v = acc > 0.f ? acc : NEG_SLOPE * acc;
        amax = fmaxf(amax, v);
    }
    xout[(size_t)gp * H_ + h] = amax;
}

// ---------------------------------------------------------------- GEMM: C = act(A @ W + b)
__global__ __launch_bounds__(256) void gemm_kernel(const float* __restrict__ A1,
                                                   const float* __restrict__ A2,
                                                   const float* __restrict__ A3,
                                                   int cat,
                                                   const float* __restrict__ Wm,
                                                   const float* __restrict__ bias,
                                                   float* __restrict__ Cm,
                                                   int M, int N, int Kd, int leaky) {
    __shared__ float sA[16][64];
    __shared__ float sB[16][64];

    int tid = threadIdx.x;
    int row0 = blockIdx.x * 64, col0 = blockIdx.y * 64;
    int tx = tid & 15, ty = tid >> 4;

    int lr  = tid >> 2;
    int lk4 = (tid & 3) * 4;
    int lkb = tid >> 4;
    int lnb = (tid & 15) * 4;

    float acc[4][4] = {};

    for (int k0 = 0; k0 < Kd; k0 += 16) {
        int arow = row0 + lr;
        int kk = k0 + lk4;
        const float* src;
        if (cat) {
            if (kk < 64)       src = A1 + (size_t)arow * 64 + kk;
            else if (kk < 128) src = A2 + (size_t)arow * 64 + (kk - 64);
            else               src = A3 + (size_t)arow * 64 + (kk - 128);
        } else {
            src = A1 + (size_t)arow * Kd + kk;
        }
        float4 av = *(const float4*)src;
        sA[lk4 + 0][lr] = av.x; sA[lk4 + 1][lr] = av.y;
        sA[lk4 + 2][lr] = av.z; sA[lk4 + 3][lr] = av.w;
        int bcol = col0 + lnb;
        float4 bv = make_float4(0.f, 0.f, 0.f, 0.f);
        if (bcol < N) bv = *(const float4*)(Wm + (size_t)(k0 + lkb) * N + bcol);
        *(float4*)&sB[lkb][lnb] = bv;
        __syncthreads();

#pragma unroll
        for (int kk2 = 0; kk2 < 16; ++kk2) {
            float4 a = *(const float4*)&sA[kk2][ty * 4];
            float4 bb = *(const float4*)&sB[kk2][tx * 4];
            acc[0][0] = fmaf(a.x, bb.x, acc[0][0]); acc[0][1] = fmaf(a.x, bb.y, acc[0][1]);
            acc[0][2] = fmaf(a.x, bb.z, acc[0][2]); acc[0][3] = fmaf(a.x, bb.w, acc[0][3]);
            acc[1][0] = fmaf(a.y, bb.x, acc[1][0]); acc[1][1] = fmaf(a.y, bb.y, acc[1][1]);
            acc[1][2] = fmaf(a.y, bb.z, acc[1][2]); acc[1][3] = fmaf(a.y, bb.w, acc[1][3]);
            acc[2][0] = fmaf(a.z, bb.x, acc[2][0]); acc[2][1] = fmaf(a.z, bb.y, acc[2][1]);
            acc[2][2] = fmaf(a.z, bb.z, acc[2][2]); acc[2][3] = fmaf(a.z, bb.w, acc[2][3]);
            acc[3][0] = fmaf(a.w, bb.x, acc[3][0]); acc[3][1] = fmaf(a.w, bb.y, acc[3][1]);
            acc[3][2] = fmaf(a.w, bb.z, acc[3][2]); acc[3][3] = fmaf(a.w, bb.w, acc[3][3]);
        }
        __syncthreads();
    }

    for (int i = 0; i < 4; ++i) {
        int row = row0 + ty * 4 + i;
        for (int j = 0; j < 4; ++j) {
            int col = col0 + tx * 4 + j;
            if (col < N) {
                float v = acc[i][j] + bias[col];
                if (leaky) v = v > 0.f ? v : NEG_SLOPE * v;
                Cm[(size_t)row * N + col] = v;
            }
        }
    }
}

// ---------------------------------------------------------------- log_softmax rows of 40
__global__ __launch_bounds__(256) void lsm_kernel(float* __restrict__ out) {
    int row = blockIdx.x * 4 + (threadIdx.x >> 6);
    int lane = threadIdx.x & 63;
    float v = -3.4e38f;
    if (lane < C_) v = out[(size_t)row * C_ + lane];
    float m = v;
#pragma unroll
    for (int s = 1; s < 64; s <<= 1) m = fmaxf(m, __shfl_xor(m, s));
    float e = (lane < C_) ? expf(v - m) : 0.f;
    float sum = e;
#pragma unroll
    for (int s = 1; s < 64; s <<= 1) sum += __shfl_xor(sum, s);
    if (lane < C_) out[(size_t)row * C_ + lane] = v - m - logf(sum);
}

// ----------------------------------------------------------------
extern "C" void kernel_launch(void* const* d_in, const int* in_sizes, int n_in,
                              void* d_out, int out_size, void* d_ws, size_t ws_size,
                              hipStream_t stream) {
    const float* x   = (const float*)d_in[0];
    const float* W1  = (const float*)d_in[2];
    const float* b1  = (const float*)d_in[3];
    const float* W2  = (const float*)d_in[4];
    const float* b2  = (const float*)d_in[5];
    const float* W3  = (const float*)d_in[6];
    const float* b3  = (const float*)d_in[7];
    const float* Wl  = (const float*)d_in[8];
    const float* bl  = (const float*)d_in[9];
    const float* Wm1 = (const float*)d_in[10];
    const float* bm1 = (const float*)d_in[11];
    const float* Wm2 = (const float*)d_in[12];
    const float* bm2 = (const float*)d_in[13];
    const float* Wo  = (const float*)d_in[14];
    const float* bo  = (const float*)d_in[15];
    float* out = (float*)d_out;

    char* ws = (char*)d_ws;
    float* x1   = (float*)(ws);                       // 8 MB
    float* x2   = (float*)(ws + 8388608);
    float* x3   = (float*)(ws + 16777216);
    int*   idx  = (int*)  (ws + 25165824);            // 2.6 MB
    float* d2   = (float*)(ws + 27787264);            // 128 KB
    float* bufA = (float*)(ws + 27918336);            // 16 MB (MLP phase)
    float* bufB = (float*)(ws + 44695552);            // 4 MB
    float* bufC = (float*)(ws + 48889856);            // 2 MB
    u64*   segl = (u64*)  (ws + 27918336);            // 21 MB, aliases bufA/B (knn phase only)

    const int SEG_GRID = (NPT / 64) * NSEG;           // 2048
    const int MRG_GRID = NPT / 64;                    // 512

    // ---- edge conv 1 (d=3)
    d2_kernel<<<NPT / 256, 256, 0, stream>>>(x, d2, 3);
    knn_seg_kernel<3><<<SEG_GRID, 64, 0, stream>>>(x, d2, segl);
    knn_merge_kernel<<<MRG_GRID, 64, 0, stream>>>(segl, idx);
    edgeconv_kernel<3><<<NPT / 4, 256, 0, stream>>>(x, idx, W1, b1, x1);
    // ---- edge conv 2 (d=64)
    d2_kernel<<<NPT / 256, 256, 0, stream>>>(x1, d2, 64);
    knn_seg_kernel<64><<<SEG_GRID, 64, 0, stream>>>(x1, d2, segl);
    knn_merge_kernel<<<MRG_GRID, 64, 0, stream>>>(segl, idx);
    edgeconv_kernel<64><<<NPT / 4, 256, 0, stream>>>(x1, idx, W2, b2, x2);
    // ---- edge conv 3 (d=64)
    d2_kernel<<<NPT / 256, 256, 0, stream>>>(x2, d2, 64);
    knn_seg_kernel<64><<<SEG_GRID, 64, 0, stream>>>(x2, d2, segl);
    knn_merge_kernel<<<MRG_GRID, 64, 0, stream>>>(segl, idx);
    edgeconv_kernel<64><<<NPT / 4, 256, 0, stream>>>(x2, idx, W3, b3, x3);

    // ---- MLP head in 8 row-chunks of 4096
    for (int c = 0; c < 8; ++c) {
        size_t r0 = (size_t)c * 4096;
        gemm_kernel<<<dim3(64, 16), 256, 0, stream>>>(x1 + r0 * 64, x2 + r0 * 64, x3 + r0 * 64,
                                                      1, Wl, bl, bufA, 4096, 1024, 192, 1);
        gemm_kernel<<<dim3(64, 4), 256, 0, stream>>>(bufA, nullptr, nullptr,
                                                     0, Wm1, bm1, bufB, 4096, 256, 1024, 1);
        gemm_kernel<<<dim3(64, 2), 256, 0, stream>>>(bufB, nullptr, nullptr,
                                                     0, Wm2, bm2, bufC, 4096, 128, 256, 1);
        gemm_kernel<<<dim3(64, 1), 256, 0, stream>>>(bufC, nullptr, nullptr,
                                                     0, Wo, bo, out + r0 * C_, 4096, 40, 128, 0);
    }
    lsm_kernel<<<NPT / 4, 256, 0, stream>>>(out);
}

// Round 5
// 3077.372 us; speedup vs baseline: 5.1548x; 1.4266x over previous
//
#include <hip/hip_runtime.h>
#include <cstddef>
#include <cstdint>

constexpr int B_ = 8, P_ = 4096, K_ = 20, H_ = 64, C_ = 40;
constexpr int NPT = B_ * P_;
constexpr int NSEG = 4, SEGLEN = P_ / NSEG;
#define NEG_SLOPE 0.2f

typedef unsigned long long u64;
typedef unsigned int u32;
typedef float v2f __attribute__((ext_vector_type(2)));

__device__ inline const float* uniform_ptr(const float* p) {
    uint64_t v = (uint64_t)p;
    u32 lo = __builtin_amdgcn_readfirstlane((u32)v);
    u32 hi = __builtin_amdgcn_readfirstlane((u32)(v >> 32));
    return (const float*)(((uint64_t)hi << 32) | lo);
}

// ---------------------------------------------------------------- d2 = sum(x*x)
template <int D>
__global__ __launch_bounds__(256) void d2_kernel(const float* __restrict__ x,
                                                 float* __restrict__ d2) {
    int i = blockIdx.x * 256 + threadIdx.x;
    if (i >= NPT) return;
    const float* r = x + (size_t)i * D;
    float s = 0.f;
    if constexpr (D % 4 == 0) {
#pragma unroll
        for (int d = 0; d < D; d += 4) {
            float4 v = *(const float4*)(r + d);
            s += v.x * v.x + v.y * v.y + v.z * v.z + v.w * v.w;
        }
    } else {
#pragma unroll
        for (int d = 0; d < D; ++d) { float v = r[d]; s += v * v; }
    }
    d2[i] = s;
}

// ---------------------------------------------------------------- knn segment pass
// One wave = 64 queries (features in VGPRs); candidates wave-uniform (scalar loads).
// Exact top-20 via replace-max list of sortable u64 keys (dist_bits<<32 | j);
// 2-deep per-lane pending buffer defers the expensive list update.
// waves_per_eu(1,2): occupancy TARGET <=2 so regalloc may keep qf[64]+lst[20] resident.
template <int D>
__global__
__attribute__((amdgpu_flat_work_group_size(64, 64)))
__attribute__((amdgpu_waves_per_eu(1, 2)))
void knn_seg_kernel(const float* __restrict__ x,
                    const float* __restrict__ d2,
                    u64* __restrict__ seglist) {
    int qg  = blockIdx.x / NSEG;
    int seg = blockIdx.x % NSEG;
    int b   = qg >> 6;
    int lane = threadIdx.x;
    int ql  = ((qg & 63) << 6) + lane;
    int q   = (b << 12) + ql;

    const float* xb  = x  + (size_t)b * P_ * D;
    const float* d2b = d2 + (size_t)b * P_;
    const float* xs  = uniform_ptr(xb);
    const float* d2s = uniform_ptr(d2b);

    float qf[D];
#pragma unroll
    for (int d = 0; d < D; ++d) qf[d] = xb[(size_t)ql * D + d];
    float qd2 = d2b[ql];

    u64 lst[K_];
#pragma unroll
    for (int s = 0; s < K_; ++s)
        lst[s] = (0x7F800000ULL << 32) | (u64)(0xFFFFFFFFu - s);   // distinct sentinels
    u64 kmax = (0x7F800000ULL << 32) | 0xFFFFFFFFULL;

    u64 p0 = ~0ULL, p1 = ~0ULL;
    int pcnt = 0;

    int j0 = seg * SEGLEN;
    for (int j = j0; j < j0 + SEGLEN; ++j) {
        float dist;
        if constexpr (D == 3) {
            float a0 = qf[0] * xs[j * 3];
            float a1 = qf[1] * xs[j * 3 + 1];
            float a2 = qf[2] * xs[j * 3 + 2];
            dist = (qd2 + d2s[j]) - 2.f * (a0 + a1 + a2);
        } else {
            v2f acc0 = {0.f, 0.f}, acc1 = {0.f, 0.f};
            const v2f* cp = (const v2f*)(xs + (size_t)j * D);
#pragma unroll
            for (int d4 = 0; d4 < D / 4; ++d4) {
                v2f c0 = cp[d4 * 2], c1 = cp[d4 * 2 + 1];
                v2f q0 = {qf[d4 * 4 + 0], qf[d4 * 4 + 1]};
                v2f q1 = {qf[d4 * 4 + 2], qf[d4 * 4 + 3]};
                acc0 = acc0 + q0 * c0;
                acc1 = acc1 + q1 * c1;
            }
            v2f acc = acc0 + acc1;
            dist = (qd2 + d2s[j]) - 2.f * (acc.x + acc.y);
        }
        if (j == ql) dist += 1e10f;
        dist = fmaxf(dist, 0.0f);
        u64 key = ((u64)__float_as_uint(dist) << 32) | (u32)j;

        bool pass = key < kmax;                  // conservative gate
        p1 = pass ? p0 : p1;
        p0 = pass ? key : p0;
        pcnt = pass ? pcnt + 1 : pcnt;

        if (__any(pcnt >= 2)) {
            u64 e0 = p1, e1 = p0;
#pragma unroll
            for (int t = 0; t < 2; ++t) {
                u64 key2 = (t == 0) ? e0 : e1;
                bool ins = key2 < kmax;
                if (__any(ins)) {
                    u64 km = kmax;
#pragma unroll
                    for (int s = 0; s < K_; ++s)
                        lst[s] = (ins && lst[s] == km) ? key2 : lst[s];
                    u64 m = lst[0];
#pragma unroll
                    for (int s = 1; s < K_; ++s) m = lst[s] > m ? lst[s] : m;
                    kmax = m;
                }
            }
            p0 = ~0ULL; p1 = ~0ULL; pcnt = 0;
        }
    }
    {
        u64 e0 = p1, e1 = p0;
#pragma unroll
        for (int t = 0; t < 2; ++t) {
            u64 key2 = (t == 0) ? e0 : e1;
            bool ins = key2 < kmax;
            if (__any(ins)) {
                u64 km = kmax;
#pragma unroll
                for (int s = 0; s < K_; ++s)
                    lst[s] = (ins && lst[s] == km) ? key2 : lst[s];
                u64 m = lst[0];
#pragma unroll
                for (int s = 1; s < K_; ++s) m = lst[s] > m ? lst[s] : m;
                kmax = m;
            }
        }
    }

    u64* outp = seglist + ((size_t)q * NSEG + seg) * K_;
#pragma unroll
    for (int s = 0; s < K_; ++s) outp[s] = lst[s];
}

// ---------------------------------------------------------------- merge NSEG segment lists
__global__ __launch_bounds__(64, 2) void knn_merge_kernel(const u64* __restrict__ seglist,
                                                          int* __restrict__ idx) {
    __shared__ u64 keys[64][NSEG * K_ + 1];
    int lane = threadIdx.x;
    int q = blockIdx.x * 64 + lane;
    const u64* src = seglist + (size_t)q * NSEG * K_;
    for (int s = 0; s < NSEG * K_; ++s) keys[lane][s] = src[s];
    int base = (q >> 12) << 12;
    int* op = idx + (size_t)q * K_;
    for (int k = 0; k < K_; ++k) {
        u64 m = keys[lane][0]; int sm = 0;
        for (int s = 1; s < NSEG * K_; ++s) {
            u64 v = keys[lane][s];
            if (v < m) { m = v; sm = s; }
        }
        keys[lane][sm] = ~0ULL;
        op[k] = base + (int)(m & 0xFFFFFFFFu);
    }
}

// ---------------------------------------------------------------- pack W[128,64] -> Wpk[64,128], bpk
__global__ __launch_bounds__(128) void pack_kernel(const float* __restrict__ W,
                                                   const float* __restrict__ b,
                                                   float* __restrict__ Wpk,
                                                   float* __restrict__ bpk) {
    int t = blockIdx.x * 128 + threadIdx.x;       // 64*128 threads
    int d = t >> 7, h2 = t & 127;
    Wpk[t] = (h2 < 64) ? W[d * 64 + h2] : W[(64 + d) * 64 + (h2 - 64)];
    if (t < 128) bpk[t] = (t < 64) ? b[t] : 0.f;
}

// ---------------------------------------------------------------- layer-1 UV (D=3, direct)
// UV[p][h]   = b[h] + sum_d x[p][d]*W[d][h]      (h<64;  U, bias included)
// UV[p][64+h]=        sum_d x[p][d]*W[3+d][h]    (V)
__global__ __launch_bounds__(256) void uv3_kernel(const float* __restrict__ x,
                                                  const float* __restrict__ W,
                                                  const float* __restrict__ b,
                                                  float* __restrict__ UV) {
    int t = blockIdx.x * 256 + threadIdx.x;       // NPT*128
    int p = t >> 7, h2 = t & 127;
    float x0 = x[p * 3], x1 = x[p * 3 + 1], x2 = x[p * 3 + 2];
    float r;
    if (h2 < 64) {
        r = b[h2] + x0 * W[h2] + x1 * W[64 + h2] + x2 * W[128 + h2];
    } else {
        int h = h2 - 64;
        r = x0 * W[192 + h] + x1 * W[256 + h] + x2 * W[320 + h];
    }
    UV[t] = r;
}

// ---------------------------------------------------------------- edge max:
// out[p][h] = max_k leaky( (U[p][h]-V[p][h]) + V[j_k][h] )
__global__ __launch_bounds__(256) void edgemax_kernel(const float* __restrict__ UV,
                                                      const int* __restrict__ idx,
                                                      float* __restrict__ xout) {
    int wv = threadIdx.x >> 6, lane = threadIdx.x & 63;
    int p = blockIdx.x * 4 + wv;
    const float* uvp = UV + (size_t)p * 128;
    float duv = uvp[lane] - uvp[64 + lane];
    const int* ip = idx + (size_t)p * K_;
    int jj[K_];
#pragma unroll
    for (int k = 0; k < K_; ++k) jj[k] = ip[k];
    float m = -3.4e38f;
#pragma unroll
    for (int k = 0; k < K_; ++k) {
        float vj = UV[(size_t)jj[k] * 128 + 64 + lane];
        float t = duv + vj;
        m = fmaxf(m, fmaxf(t, NEG_SLOPE * t));    // leaky via max (slope<1)
    }
    xout[(size_t)p * H_ + lane] = m;
}

// ---------------------------------------------------------------- GEMM: C = act(A @ W + b)
// LDS stride 68: kills 4-way write conflicts, keeps float4 alignment.
__global__ __launch_bounds__(256) void gemm_kernel(const float* __restrict__ A1,
                                                   const float* __restrict__ A2,
                                                   const float* __restrict__ A3,
                                                   int cat,
                                                   const float* __restrict__ Wm,
                                                   const float* __restrict__ bias,
                                                   float* __restrict__ Cm,
                                                   int M, int N, int Kd, int leaky) {
    __shared__ float sA[16][68];
    __shared__ float sB[16][68];

    int tid = threadIdx.x;
    int row0 = blockIdx.x * 64, col0 = blockIdx.y * 64;
    int tx = tid & 15, ty = tid >> 4;

    int lr  = tid >> 2;
    int lk4 = (tid & 3) * 4;
    int lkb = tid >> 4;
    int lnb = (tid & 15) * 4;

    float acc[4][4] = {};

    for (int k0 = 0; k0 < Kd; k0 += 16) {
        int arow = row0 + lr;
        int kk = k0 + lk4;
        const float* src;
        if (cat) {
            if (kk < 64)       src = A1 + (size_t)arow * 64 + kk;
            else if (kk < 128) src = A2 + (size_t)arow * 64 + (kk - 64);
            else               src = A3 + (size_t)arow * 64 + (kk - 128);
        } else {
            src = A1 + (size_t)arow * Kd + kk;
        }
        float4 av = *(const float4*)src;
        sA[lk4 + 0][lr] = av.x; sA[lk4 + 1][lr] = av.y;
        sA[lk4 + 2][lr] = av.z; sA[lk4 + 3][lr] = av.w;
        int bcol = col0 + lnb;
        float4 bv = make_float4(0.f, 0.f, 0.f, 0.f);
        if (bcol < N) bv = *(const float4*)(Wm + (size_t)(k0 + lkb) * N + bcol);
        *(float4*)&sB[lkb][lnb] = bv;
        __syncthreads();

#pragma unroll
        for (int kk2 = 0; kk2 < 16; ++kk2) {
            float4 a = *(const float4*)&sA[kk2][ty * 4];
            float4 bb = *(const float4*)&sB[kk2][tx * 4];
            acc[0][0] = fmaf(a.x, bb.x, acc[0][0]); acc[0][1] = fmaf(a.x, bb.y, acc[0][1]);
            acc[0][2] = fmaf(a.x, bb.z, acc[0][2]); acc[0][3] = fmaf(a.x, bb.w, acc[0][3]);
            acc[1][0] = fmaf(a.y, bb.x, acc[1][0]); acc[1][1] = fmaf(a.y, bb.y, acc[1][1]);
            acc[1][2] = fmaf(a.y, bb.z, acc[1][2]); acc[1][3] = fmaf(a.y, bb.w, acc[1][3]);
            acc[2][0] = fmaf(a.z, bb.x, acc[2][0]); acc[2][1] = fmaf(a.z, bb.y, acc[2][1]);
            acc[2][2] = fmaf(a.z, bb.z, acc[2][2]); acc[2][3] = fmaf(a.z, bb.w, acc[2][3]);
            acc[3][0] = fmaf(a.w, bb.x, acc[3][0]); acc[3][1] = fmaf(a.w, bb.y, acc[3][1]);
            acc[3][2] = fmaf(a.w, bb.z, acc[3][2]); acc[3][3] = fmaf(a.w, bb.w, acc[3][3]);
        }
        __syncthreads();
    }

    for (int i = 0; i < 4; ++i) {
        int row = row0 + ty * 4 + i;
        for (int j = 0; j < 4; ++j) {
            int col = col0 + tx * 4 + j;
            if (col < N) {
                float v = acc[i][j] + bias[col];
                if (leaky) v = v > 0.f ? v : NEG_SLOPE * v;
                Cm[(size_t)row * N + col] = v;
            }
        }
    }
}

// ---------------------------------------------------------------- log_softmax rows of 40
__global__ __launch_bounds__(256) void lsm_kernel(float* __restrict__ out) {
    int row = blockIdx.x * 4 + (threadIdx.x >> 6);
    int lane = threadIdx.x & 63;
    float v = -3.4e38f;
    if (lane < C_) v = out[(size_t)row * C_ + lane];
    float m = v;
#pragma unroll
    for (int s = 1; s < 64; s <<= 1) m = fmaxf(m, __shfl_xor(m, s));
    float e = (lane < C_) ? expf(v - m) : 0.f;
    float sum = e;
#pragma unroll
    for (int s = 1; s < 64; s <<= 1) sum += __shfl_xor(sum, s);
    if (lane < C_) out[(size_t)row * C_ + lane] = v - m - logf(sum);
}

// ----------------------------------------------------------------
extern "C" void kernel_launch(void* const* d_in, const int* in_sizes, int n_in,
                              void* d_out, int out_size, void* d_ws, size_t ws_size,
                              hipStream_t stream) {
    const float* x   = (const float*)d_in[0];
    const float* W1  = (const float*)d_in[2];
    const float* b1  = (const float*)d_in[3];
    const float* W2  = (const float*)d_in[4];
    const float* b2  = (const float*)d_in[5];
    const float* W3  = (const float*)d_in[6];
    const float* b3  = (const float*)d_in[7];
    const float* Wl  = (const float*)d_in[8];
    const float* bl  = (const float*)d_in[9];
    const float* Wm1 = (const float*)d_in[10];
    const float* bm1 = (const float*)d_in[11];
    const float* Wm2 = (const float*)d_in[12];
    const float* bm2 = (const float*)d_in[13];
    const float* Wo  = (const float*)d_in[14];
    const float* bo  = (const float*)d_in[15];
    float* out = (float*)d_out;

    char* ws = (char*)d_ws;
    float* x1   = (float*)(ws);                       // 8 MB
    float* x2   = (float*)(ws + 8388608);             // 8 MB
    float* x3   = (float*)(ws + 16777216);            // 8 MB
    int*   idx  = (int*)  (ws + 25165824);            // 2.62 MB
    float* d2   = (float*)(ws + 27787264);            // 128 KB
    float* bufA = (float*)(ws + 27918336);            // 16 MB (MLP phase)
    float* bufB = (float*)(ws + 44695552);            // 4 MB  (MLP phase)
    float* bufC = (float*)(ws + 48889856);            // 2 MB  (MLP phase)
    u64*   segl = (u64*)  (ws + 27918336);            // 20 MB (knn phase, aliases bufA+bufB)
    float* UV   = (float*)(ws + 27918336);            // 16 MB (edgeconv phase, aliases bufA)
    float* Wpk  = (float*)(ws + 44695552);            // 32 KB (edgeconv phase, aliases bufB)
    float* bpk  = (float*)(ws + 44728320);            // 512 B

    const int SEG_GRID = (NPT / 64) * NSEG;           // 2048
    const int MRG_GRID = NPT / 64;                    // 512

    // ---- layer 1 (D=3)
    d2_kernel<3><<<NPT / 256, 256, 0, stream>>>(x, d2);
    knn_seg_kernel<3><<<SEG_GRID, 64, 0, stream>>>(x, d2, segl);
    knn_merge_kernel<<<MRG_GRID, 64, 0, stream>>>(segl, idx);
    uv3_kernel<<<NPT * 128 / 256, 256, 0, stream>>>(x, W1, b1, UV);
    edgemax_kernel<<<NPT / 4, 256, 0, stream>>>(UV, idx, x1);
    // ---- layer 2 (D=64)
    d2_kernel<64><<<NPT / 256, 256, 0, stream>>>(x1, d2);
    knn_seg_kernel<64><<<SEG_GRID, 64, 0, stream>>>(x1, d2, segl);
    knn_merge_kernel<<<MRG_GRID, 64, 0, stream>>>(segl, idx);
    pack_kernel<<<64, 128, 0, stream>>>(W2, b2, Wpk, bpk);
    gemm_kernel<<<dim3(NPT / 64, 2), 256, 0, stream>>>(x1, nullptr, nullptr, 0,
                                                       Wpk, bpk, UV, NPT, 128, 64, 0);
    edgemax_kernel<<<NPT / 4, 256, 0, stream>>>(UV, idx, x2);
    // ---- layer 3 (D=64)
    d2_kernel<64><<<NPT / 256, 256, 0, stream>>>(x2, d2);
    knn_seg_kernel<64><<<SEG_GRID, 64, 0, stream>>>(x2, d2, segl);
    knn_merge_kernel<<<MRG_GRID, 64, 0, stream>>>(segl, idx);
    pack_kernel<<<64, 128, 0, stream>>>(W3, b3, Wpk, bpk);
    gemm_kernel<<<dim3(NPT / 64, 2), 256, 0, stream>>>(x2, nullptr, nullptr, 0,
                                                       Wpk, bpk, UV, NPT, 128, 64, 0);
    edgemax_kernel<<<NPT / 4, 256, 0, stream>>>(UV, idx, x3);

    // ---- MLP head in 8 row-chunks of 4096
    for (int c = 0; c < 8; ++c) {
        size_t r0 = (size_t)c * 4096;
        gemm_kernel<<<dim3(64, 16), 256, 0, stream>>>(x1 + r0 * 64, x2 + r0 * 64, x3 + r0 * 64,
                                                      1, Wl, bl, bufA, 4096, 1024, 192, 1);
        gemm_kernel<<<dim3(64, 4), 256, 0, stream>>>(bufA, nullptr, nullptr,
                                                     0, Wm1, bm1, bufB, 4096, 256, 1024, 1);
        gemm_kernel<<<dim3(64, 2), 256, 0, stream>>>(bufB, nullptr, nullptr,
                                                     0, Wm2, bm2, bufC, 4096, 128, 256, 1);
        gemm_kernel<<<dim3(64, 1), 256, 0, stream>>>(bufC, nullptr, nullptr,
                                                     0, Wo, bo, out + r0 * C_, 4096, 40, 128, 0);
    }
    lsm_kernel<<<NPT / 4, 256, 0, stream>>>(out);
}